// Round 3
// baseline (346.793 us; speedup 1.0000x reference)
//
#include <hip/hip_runtime.h>
#include <math.h>

#define IN_DIM 28
#define BOND   10
#define OUT_D  10
#define BLOCK  256
#define H0_STRIDE 11     // odd stride -> conflict-free per-thread h0 spill slots
#define THRESH 35.0f     // sigmoid(c)==1.0f in fp32 for c>~17.4; 2x margin

// One thread = one sample. Three tiers, each a RIGOROUS bound given the
// runtime-verified preconditions (all x >= 0, all weights >= 0):
//
//  tier-1 (56 FMA + 14 LDS b128):  c[o]+bias[o] >= A*B + biasmin
//          A = sum_i x0[i]*v[i],  v[i] = min_b t0[i][b]      (A >= 0)
//          B = sum_j x1[j]*u[j],  u[j] = min_o sum_b t1[j][b][o]
//  tier-2 (600 FMA + 140 LDS b128): c[o]+bias[o] >= h0min*s1[o]+bias[o]
//          s1[o] = sum_j x1[j] * (sum_b t1[j][b][o])  (bond-collapsed)
//  tier-3: exact einsum + sigmoid.
//
// On this benchmark (uniform[0,1) data) the true c ~ 490 >> 17.4, so sigmoid
// saturates to exactly 1.0f everywhere (confirmed: absmax==0.0 across three
// rounds with different FMA orderings). Tier-1 passes for ~all waves; the
// kernel is then HBM-bound: 224B read + 40B write per sample ~ 277MB -> ~44us.
__global__ __launch_bounds__(BLOCK) void tn_kernel(
    const float* __restrict__ x,     // [N, 56]
    const float* __restrict__ t0,    // [28,10]   (i,b)
    const float* __restrict__ t1,    // [28,10,10](j,b,o)
    const float* __restrict__ bias,  // [10]
    float* __restrict__ out,         // [N,10]
    int n_total)
{
    __shared__ __align__(16) float lt0[IN_DIM * BOND];    // 280, [i][b]
    __shared__ __align__(16) float lT1s[IN_DIM * OUT_D];  // 280, [j][o]=sum_b t1
    __shared__ __align__(16) float luv[2 * IN_DIM];       // [0..27]=v, [28..55]=u
    __shared__ float lbias[OUT_D];
    __shared__ float lh0[BLOCK * H0_STRIDE];              // tier-3 h0 spill
    __shared__ int   wneg;                                // any weight < 0?
    __shared__ float sbiasmin;

    const int tid = threadIdx.x;
    const int n = blockIdx.x * BLOCK + tid;
    const int nc = (n < n_total) ? n : (n_total - 1);

    if (tid == 0) wneg = 0;
    __syncthreads();          // before any loads are issued -> no vmcnt drain

    // ---- issue this sample's 14 float4 loads first (overlap with staging) ----
    float4 xq[14];
    const float4* __restrict__ xrow =
        reinterpret_cast<const float4*>(x + (size_t)nc * (2 * IN_DIM));
#pragma unroll
    for (int k = 0; k < 14; ++k) xq[k] = xrow[k];

    // ---- one-time cooperative staging (L2-hit reads; overlapped with x) ----
    int localneg = 0;
    for (int idx = tid; idx < IN_DIM * BOND; idx += BLOCK) {
        const float w = t0[idx];
        localneg |= (w < 0.0f);
        lt0[idx] = w;
    }
    for (int idx = tid; idx < IN_DIM * OUT_D; idx += BLOCK) {
        const int j = idx / OUT_D;
        const int o = idx - j * OUT_D;
        const float* __restrict__ p = t1 + j * (BOND * OUT_D) + o;
        float s = 0.0f;
#pragma unroll
        for (int b = 0; b < BOND; ++b) {
            const float w = p[b * OUT_D];
            localneg |= (w < 0.0f);
            s += w;
        }
        lT1s[idx] = s;
    }
    if (tid < IN_DIM) {                     // v[i] = min_b t0[i][b]
        const float* __restrict__ p = t0 + tid * BOND;
        float m = p[0];
#pragma unroll
        for (int b = 1; b < BOND; ++b) m = fminf(m, p[b]);
        luv[tid] = m;
    } else if (tid >= 32 && tid < 32 + IN_DIM) {   // u[j] = min_o sum_b t1[j][b][o]
        const int j = tid - 32;
        const float* __restrict__ p = t1 + j * (BOND * OUT_D);
        float m = 3.4e38f;
#pragma unroll
        for (int o = 0; o < OUT_D; ++o) {
            float s = 0.0f;
#pragma unroll
            for (int b = 0; b < BOND; ++b) s += p[b * OUT_D + o];
            m = fminf(m, s);
        }
        luv[IN_DIM + j] = m;
    } else if (tid >= 64 && tid < 64 + OUT_D) {
        lbias[tid - 64] = bias[tid - 64];
    } else if (tid == 96) {
        float bm = bias[0];
#pragma unroll
        for (int o = 1; o < OUT_D; ++o) bm = fminf(bm, bias[o]);
        sbiasmin = bm;
    }
    if (localneg) wneg = 1;   // benign race: only 1s written after init+barrier
    __syncthreads();

    // ---- unpack to compile-time-indexed registers; track min for validity ----
    float xe[2 * IN_DIM];
    float xmin = 0.0f;
#pragma unroll
    for (int k = 0; k < 14; ++k) {
        xe[4 * k + 0] = xq[k].x;
        xe[4 * k + 1] = xq[k].y;
        xe[4 * k + 2] = xq[k].z;
        xe[4 * k + 3] = xq[k].w;
        xmin = fminf(xmin, fminf(fminf(xq[k].x, xq[k].y), fminf(xq[k].z, xq[k].w)));
    }

    const int   wn = wneg;
    const float bmadd = sbiasmin;

    // ================= tier-1: 56 FMA, 14 b128 broadcasts =================
    float A = 0.0f, B = 0.0f;
    {
        const float4* __restrict__ uv = reinterpret_cast<const float4*>(luv);
#pragma unroll
        for (int c = 0; c < 7; ++c) {        // x0 . v
            const float4 w = uv[c];
            const int f = 4 * c;
            A = fmaf(xe[f + 0], w.x, A); A = fmaf(xe[f + 1], w.y, A);
            A = fmaf(xe[f + 2], w.z, A); A = fmaf(xe[f + 3], w.w, A);
        }
#pragma unroll
        for (int c = 7; c < 14; ++c) {       // x1 . u  (xe index == luv index)
            const float4 w = uv[c];
            const int f = 4 * c;
            B = fmaf(xe[f + 0], w.x, B); B = fmaf(xe[f + 1], w.y, B);
            B = fmaf(xe[f + 2], w.z, B); B = fmaf(xe[f + 3], w.w, B);
        }
    }
    // valid when x>=0 and weights>=0 (then v,u>=0 so A>=0):
    //   c[o]+bias[o] >= A*B + biasmin
    const bool sat1 = (xmin >= 0.0f) && (wn == 0) && (fmaf(A, B, bmadd) > THRESH);
    if (__all(sat1)) {
        if (n < n_total) {
            float2* __restrict__ op =
                reinterpret_cast<float2*>(out + (size_t)n * OUT_D);
            const float2 one2 = make_float2(1.0f, 1.0f);
#pragma unroll
            for (int q = 0; q < 5; ++q) op[q] = one2;
        }
        return;
    }

    // ================= tier-2: 600 FMA bound (rare) =================
    float h0[BOND];
#pragma unroll
    for (int b = 0; b < BOND; ++b) h0[b] = 0.0f;
    {
        const float4* __restrict__ w0 = reinterpret_cast<const float4*>(lt0);
#pragma unroll
        for (int c = 0; c < 70; ++c) {
            const float4 w = w0[c];
            const int f = 4 * c;
            h0[(f + 0) % 10] = fmaf(xe[(f + 0) / 10], w.x, h0[(f + 0) % 10]);
            h0[(f + 1) % 10] = fmaf(xe[(f + 1) / 10], w.y, h0[(f + 1) % 10]);
            h0[(f + 2) % 10] = fmaf(xe[(f + 2) / 10], w.z, h0[(f + 2) % 10]);
            h0[(f + 3) % 10] = fmaf(xe[(f + 3) / 10], w.w, h0[(f + 3) % 10]);
        }
    }
    float h0min = h0[0];
#pragma unroll
    for (int b = 1; b < BOND; ++b) h0min = fminf(h0min, h0[b]);

    float s1[OUT_D];
#pragma unroll
    for (int o = 0; o < OUT_D; ++o) s1[o] = 0.0f;
    {
        const float4* __restrict__ ws = reinterpret_cast<const float4*>(lT1s);
#pragma unroll
        for (int c = 0; c < 70; ++c) {
            const float4 w = ws[c];
            const int f = 4 * c;
            s1[(f + 0) % 10] = fmaf(xe[28 + (f + 0) / 10], w.x, s1[(f + 0) % 10]);
            s1[(f + 1) % 10] = fmaf(xe[28 + (f + 1) / 10], w.y, s1[(f + 1) % 10]);
            s1[(f + 2) % 10] = fmaf(xe[28 + (f + 2) / 10], w.z, s1[(f + 2) % 10]);
            s1[(f + 3) % 10] = fmaf(xe[28 + (f + 3) / 10], w.w, s1[(f + 3) % 10]);
        }
    }
    float bmin2 = fmaf(h0min, s1[0], lbias[0]);
#pragma unroll
    for (int o = 1; o < OUT_D; ++o)
        bmin2 = fminf(bmin2, fmaf(h0min, s1[o], lbias[o]));

    const bool sat2 = (xmin >= 0.0f) && (wn == 0) && (bmin2 > THRESH);
    if (__all(sat2)) {
        if (n < n_total) {
            float2* __restrict__ op =
                reinterpret_cast<float2*>(out + (size_t)n * OUT_D);
            const float2 one2 = make_float2(1.0f, 1.0f);
#pragma unroll
            for (int q = 0; q < 5; ++q) op[q] = one2;
        }
        return;
    }

    // ================= tier-3: exact (statistically never) =================
#pragma unroll
    for (int b = 0; b < BOND; ++b) lh0[tid * H0_STRIDE + b] = h0[b];

    float acc[OUT_D];
#pragma unroll
    for (int o = 0; o < OUT_D; ++o) acc[o] = lbias[o];

#pragma unroll 1
    for (int b = 0; b < BOND; ++b) {
        const float hb = lh0[tid * H0_STRIDE + b];
        const float* __restrict__ wb = t1 + b * OUT_D;   // t1[j*100 + b*10 + o]
        float h1[OUT_D];
#pragma unroll
        for (int o = 0; o < OUT_D; ++o) h1[o] = 0.0f;
#pragma unroll
        for (int j = 0; j < IN_DIM; ++j) {
            const float x1j = xe[IN_DIM + j];
#pragma unroll
            for (int o = 0; o < OUT_D; ++o)
                h1[o] = fmaf(x1j, wb[j * (BOND * OUT_D) + o], h1[o]);
        }
#pragma unroll
        for (int o = 0; o < OUT_D; ++o) acc[o] = fmaf(hb, h1[o], acc[o]);
    }

    if (n < n_total) {
        float2* __restrict__ op =
            reinterpret_cast<float2*>(out + (size_t)n * OUT_D);
#pragma unroll
        for (int o = 0; o < OUT_D; o += 2) {
            float2 r;
            r.x = 1.0f / (1.0f + __expf(-acc[o]));
            r.y = 1.0f / (1.0f + __expf(-acc[o + 1]));
            op[o >> 1] = r;
        }
    }
}

extern "C" void kernel_launch(void* const* d_in, const int* in_sizes, int n_in,
                              void* d_out, int out_size, void* d_ws, size_t ws_size,
                              hipStream_t stream) {
    const float* x    = (const float*)d_in[0];
    const float* t0   = (const float*)d_in[1];
    const float* t1   = (const float*)d_in[2];
    const float* bias = (const float*)d_in[3];
    float* out        = (float*)d_out;

    const int n_total = in_sizes[0] / (2 * IN_DIM);
    const int grid = (n_total + BLOCK - 1) / BLOCK;
    tn_kernel<<<grid, BLOCK, 0, stream>>>(x, t0, t1, bias, out, n_total);
}